// Round 1
// baseline (193.675 us; speedup 1.0000x reference)
//
#include <hip/hip_runtime.h>
#include <math.h>

#define TOPK 4
#define WAVE 64
#define ROUNDS 5                 // 5 DMA rounds x 64 lanes x 16 B = 5120 B / tile
#define STAGE (ROUNDS * 256)     // 1280 floats staged (mean 1024 + ~7.5 sigma)
#define PAD 8                    // pipeline overread pad (reads reach STAGE+3)
#define GRID 3840                // 15 single-wave blocks per CU (LDS 2x5.15KB -> 15/CU)

// Fire-and-forget global->LDS DMA for one tile. LDS dest is wave-uniform
// (hardware places lane i at dst + 16*i). Source clamped to the tile's own
// last 16B line (chi) so overfetch rounds hit L2 instead of pulling the
// neighbor tile's data from HBM; clamped lanes write garbage the masked
// scan never inserts.
__device__ __forceinline__ void dma_tile(const float* __restrict__ scores,
                                         int base, int chi, float* dst, int lane)
{
#pragma unroll
    for (int r = 0; r < ROUNDS; ++r) {
        int src = base + (r << 8) + (lane << 2);
        src = src < chi ? src : chi;
        __builtin_amdgcn_global_load_lds(
            (const __attribute__((address_space(1))) void*)(scores + src),
            (__attribute__((address_space(3))) void*)(dst + (r << 8)),
            16, 0, 0);
    }
}

__global__ __launch_bounds__(WAVE) void segment_top4_kernel(
    const int* __restrict__ row_ptr,
    const float* __restrict__ scores,
    float* __restrict__ vals_out,   // [N,4] float32
    float* __restrict__ idx_out,    // [N,4] indices as float32
    int n_nodes, int n_edges, int n_tiles)
{
    __shared__ float lds[2][STAGE + PAD];

    int t = blockIdx.x;
    if (t >= n_tiles) return;
    int lane = threadIdx.x;
    int odd  = lane & 1;             // lane pair (2n,2n+1) handles node tile*32+n
    int G = gridDim.x;
    int ghi = n_edges - 4;

    // Prologue: tile t's DMA + per-lane segment bounds.
    int base = row_ptr[t << 5] & ~15;                     // uniform -> s_load
    int thi  = row_ptr[min((t << 5) + 32, n_nodes)];      // uniform -> s_load
    int chi  = max(0, min(ghi, (thi - 1) & ~3));          // tile-local src clamp
    dma_tile(scores, base, chi, lds[0], lane);
    int node = (t << 5) + (lane >> 1);
    int sb = 0, se = 0;
    if (node < n_nodes) { sb = row_ptr[node]; se = row_ptr[node + 1]; }

    int cur = 0;
    while (true) {
        int tn = t + G;
        bool has_next = (tn < n_tiles);                   // block-uniform branch
        int nbase = 0, nsb = 0, nse = 0;
        if (has_next) {
            // Prefetch next tile's bounds BEFORE its DMA (fence pins order),
            // so at the wait below the 5 newest vmem ops are exactly the DMA.
            int nnode = (tn << 5) + (lane >> 1);
            if (nnode < n_nodes) { nsb = row_ptr[nnode]; nse = row_ptr[nnode + 1]; }
            nbase = row_ptr[tn << 5] & ~15;               // uniform -> s_load
            int nthi = row_ptr[min((tn << 5) + 32, n_nodes)];
            int nchi = max(0, min(ghi, (nthi - 1) & ~3));
            asm volatile("" ::: "memory");                // compile-time order fence
            dma_tile(scores, nbase, nchi, lds[cur ^ 1], lane);
            // Partial drain: wait for everything EXCEPT the ROUNDS(=5)
            // just-issued next-tile DMAs. Never vmcnt(0) in steady state.
            asm volatile("s_waitcnt vmcnt(5)" ::: "memory");
        } else {
            asm volatile("s_waitcnt vmcnt(0)" ::: "memory");
        }

        // ---- scan tile t from lds[cur] ----
        // Each lane scans half of its node's segment: even lane [sb,mid),
        // odd lane [mid,se). Contiguous split => even-lane indices < odd-lane
        // indices, so the strict-'>' merge below preserves the reference
        // tie-break (score desc, index asc) exactly.
        float v0 = -INFINITY, v1 = -INFINITY, v2 = -INFINITY, v3 = -INFINITY;
        int   i0 = -1, i1 = -1, i2 = -1, i3 = -1;
        auto ins = [&](float s, int ei) {
            bool g0 = s > v0, g1 = s > v1, g2 = s > v2, g3 = s > v3;
            v3 = g3 ? (g2 ? v2 : s) : v3;  i3 = g3 ? (g2 ? i2 : ei) : i3;
            v2 = g2 ? (g1 ? v1 : s) : v2;  i2 = g2 ? (g1 ? i1 : ei) : i2;
            v1 = g1 ? (g0 ? v0 : s) : v1;  i1 = g1 ? (g0 ? i0 : ei) : i1;
            v0 = g0 ? s : v0;              i0 = g0 ? ei : i0;
        };

        int mid = (sb + se + 1) >> 1;
        int lo  = odd ? mid : sb;
        int hi  = odd ? se  : mid;

        const float* buf = lds[cur];
        int lim = min(hi, base + STAGE);
        unsigned rng = (unsigned)max(lim - lo, 0);        // live iff (e-lo) < rng
        int e0 = lo & ~3;                                 // 16B-aligned -> b128 reads
        int lp = min(max(e0 - base, 0), STAGE);           // clamped degenerate preload
        float4 q = *(const float4*)(buf + lp);
        for (int e = e0; e < lim; e += 4) {
            float4 qn = *(const float4*)(buf + (e + 4 - base));  // 1-ahead prefetch
            unsigned off = (unsigned)(e - lo);            // wraps below lo -> masked
            ins((off      < rng) ? q.x : -INFINITY, e);
            ins((off + 1u < rng) ? q.y : -INFINITY, e + 1);
            ins((off + 2u < rng) ? q.z : -INFINITY, e + 2);
            ins((off + 3u < rng) ? q.w : -INFINITY, e + 3);
            q = qn;
        }
        // Overflow fallback: segment runs past the staged window (~never).
        for (int e = max(lo, lim); e < hi; ++e)
            ins(scores[e], e);

        // ---- pair merge: odd lane's sorted top4 into even lane's ----
        auto swzf = [](float x) {
            return __int_as_float(__builtin_amdgcn_ds_swizzle(__float_as_int(x), 0x041F));
        };
        auto swzi = [](int x) { return __builtin_amdgcn_ds_swizzle(x, 0x041F); };
        float w0 = swzf(v0), w1 = swzf(v1), w2 = swzf(v2), w3 = swzf(v3);
        int   j0 = swzi(i0), j1 = swzi(i1), j2 = swzi(i2), j3 = swzi(i3);
        // Incoming sorted desc; incumbents (even lane) have smaller indices,
        // strict '>' keeps them on ties. -inf slots never insert.
        ins(w0, j0); ins(w1, j1); ins(w2, j2); ins(w3, j3);

        // ---- store (even lanes own the merged result) ----
        if (!odd && node < n_nodes) {
            float4 vo, io;
            vo.x = v0; vo.y = v1; vo.z = v2; vo.w = v3;
            io.x = (float)i0; io.y = (float)i1; io.z = (float)i2; io.w = (float)i3;
            *(float4*)(vals_out + (size_t)node * 4) = vo;
            *(float4*)(idx_out + (size_t)node * 4) = io;
        }

        if (!has_next) break;
        t = tn; node = (tn << 5) + (lane >> 1);
        sb = nsb; se = nse; base = nbase; cur ^= 1;
    }
}

extern "C" void kernel_launch(void* const* d_in, const int* in_sizes, int n_in,
                              void* d_out, int out_size, void* d_ws, size_t ws_size,
                              hipStream_t stream)
{
    const int*   row_ptr = (const int*)d_in[0];
    const float* scores  = (const float*)d_in[1];
    int n_nodes = in_sizes[0] - 1;
    int n_edges = in_sizes[1];
    int n_tiles = (n_nodes + 31) >> 5;

    float* out      = (float*)d_out;
    float* vals_out = out;                           // first N*4 floats
    float* idx_out  = out + (size_t)n_nodes * TOPK;  // next N*4 floats (idx as f32)

    int grid = n_tiles < GRID ? n_tiles : GRID;
    segment_top4_kernel<<<grid, WAVE, 0, stream>>>(
        row_ptr, scores, vals_out, idx_out, n_nodes, n_edges, n_tiles);
}

// Round 2
// 181.951 us; speedup vs baseline: 1.0644x; 1.0644x over previous
//
#include <hip/hip_runtime.h>
#include <math.h>

#define TOPK 4
#define WAVE 64
#define ROUNDS 9                 // 9 DMA rounds x 64 lanes x 16 B = 9216 B / tile
#define STAGE (ROUNDS * 256)     // 2304 floats staged per tile (mean 2048 + 5.6 sigma)
#define PAD 8                    // scan pipeline overread pad (reads reach STAGE+6)
#define GRID 2048                // 8 single-wave blocks per CU (LDS 2x9.2KB -> 8/CU)

// Fire-and-forget global->LDS DMA for one tile. LDS dest is wave-uniform
// (hardware places lane i at dst + 16*i). Source clamped in-array; clamped
// lanes write garbage that the masked scan never inserts.
__device__ __forceinline__ void dma_tile(const float* __restrict__ scores,
                                         int base, int clamp_hi, float* dst, int lane)
{
#pragma unroll
    for (int r = 0; r < ROUNDS; ++r) {
        int src = base + (r << 8) + (lane << 2);
        src = src < clamp_hi ? src : clamp_hi;
        __builtin_amdgcn_global_load_lds(
            (const __attribute__((address_space(1))) void*)(scores + src),
            (__attribute__((address_space(3))) void*)(dst + (r << 8)),
            16, 0, 0);
    }
}

__global__ __launch_bounds__(WAVE) void segment_top4_kernel(
    const int* __restrict__ row_ptr,
    const float* __restrict__ scores,
    float* __restrict__ vals_out,   // [N,4] float32
    float* __restrict__ idx_out,    // [N,4] indices as float32
    int n_nodes, int n_edges, int n_tiles)
{
    __shared__ float lds[2][STAGE + PAD];

    int t = blockIdx.x;
    if (t >= n_tiles) return;
    int lane = threadIdx.x;
    int G = gridDim.x;
    int clamp_hi = n_edges - 4;

    // Prologue: tile t's DMA + per-lane segment bounds.
    int base = row_ptr[t << 6] & ~15;                 // uniform -> s_load
    dma_tile(scores, base, clamp_hi, lds[0], lane);
    int node = (t << 6) + lane;
    int sb = 0, se = 0;
    if (node < n_nodes) { sb = row_ptr[node]; se = row_ptr[node + 1]; }

    int cur = 0;
    while (true) {
        int tn = t + G;
        bool has_next = (tn < n_tiles);               // block-uniform branch
        int nbase = 0, nsb = 0, nse = 0;
        if (has_next) {
            // Prefetch next tile's bounds BEFORE its DMA (fence pins order),
            // so at the wait below the 9 newest vmem ops are exactly the DMA.
            int nnode = (tn << 6) + lane;
            if (nnode < n_nodes) { nsb = row_ptr[nnode]; nse = row_ptr[nnode + 1]; }
            nbase = row_ptr[tn << 6] & ~15;           // uniform -> s_load (lgkm)
            asm volatile("" ::: "memory");            // compile-time order fence
            dma_tile(scores, nbase, clamp_hi, lds[cur ^ 1], lane);
            // AITER-style partial drain: wait for everything EXCEPT the 9
            // just-issued next-tile DMAs -> tile t's data is in LDS while
            // 9.2 KB stays in flight through the entire scan. Never vmcnt(0).
            asm volatile("s_waitcnt vmcnt(9)" ::: "memory");
        } else {
            asm volatile("s_waitcnt vmcnt(0)" ::: "memory");
        }

        // ---- scan tile t from lds[cur] ----
        // f32 value + int index instead of packed u64 key: strict '>' while
        // scanning in increasing edge order reproduces the reference
        // tie-break (score desc, index asc) exactly. Masked slots insert
        // -inf, which never displaces anything.
        float v0 = -INFINITY, v1 = -INFINITY, v2 = -INFINITY, v3 = -INFINITY;
        int   i0 = -1, i1 = -1, i2 = -1, i3 = -1;
        auto ins = [&](float s, int ei) {
            bool g0 = s > v0, g1 = s > v1, g2 = s > v2, g3 = s > v3;
            v3 = g3 ? (g2 ? v2 : s) : v3;  i3 = g3 ? (g2 ? i2 : ei) : i3;
            v2 = g2 ? (g1 ? v1 : s) : v2;  i2 = g2 ? (g1 ? i1 : ei) : i2;
            v1 = g1 ? (g0 ? v0 : s) : v1;  i1 = g1 ? (g0 ? i0 : ei) : i1;
            v0 = g0 ? s : v0;              i0 = g0 ? ei : i0;
        };

        const float* buf = lds[cur];
        int lim = min(se, base + STAGE);
        unsigned rng = (unsigned)max(lim - sb, 0);    // live iff (e-sb) < rng
        int e0 = sb & ~3;                             // 16B-aligned -> ds_read_b128
        int lp = min(max(e0 - base, 0), STAGE);       // clamped degenerate preload
        float4 q = *(const float4*)(buf + lp);
        for (int e = e0; e < lim; e += 4) {
            float4 qn = *(const float4*)(buf + (e + 4 - base));  // 1-ahead prefetch
            unsigned off = (unsigned)(e - sb);        // wraps below sb -> masked
            ins((off      < rng) ? q.x : -INFINITY, e);
            ins((off + 1u < rng) ? q.y : -INFINITY, e + 1);
            ins((off + 2u < rng) ? q.z : -INFINITY, e + 2);
            ins((off + 3u < rng) ? q.w : -INFINITY, e + 3);
            q = qn;
        }
        // Overflow fallback: segment runs past the staged window (~never).
        for (int e = max(sb, lim); e < se; ++e)
            ins(scores[e], e);

        // ---- store ----
        if (node < n_nodes) {
            float4 vo, io;
            vo.x = v0; vo.y = v1; vo.z = v2; vo.w = v3;
            io.x = (float)i0; io.y = (float)i1; io.z = (float)i2; io.w = (float)i3;
            *(float4*)(vals_out + (size_t)node * 4) = vo;
            *(float4*)(idx_out + (size_t)node * 4) = io;
        }

        if (!has_next) break;
        t = tn; node = (tn << 6) + lane;
        sb = nsb; se = nse; base = nbase; cur ^= 1;
    }
}

extern "C" void kernel_launch(void* const* d_in, const int* in_sizes, int n_in,
                              void* d_out, int out_size, void* d_ws, size_t ws_size,
                              hipStream_t stream)
{
    const int*   row_ptr = (const int*)d_in[0];
    const float* scores  = (const float*)d_in[1];
    int n_nodes = in_sizes[0] - 1;
    int n_edges = in_sizes[1];
    int n_tiles = (n_nodes + 63) >> 6;

    float* out      = (float*)d_out;
    float* vals_out = out;                           // first N*4 floats
    float* idx_out  = out + (size_t)n_nodes * TOPK;  // next N*4 floats (idx as f32)

    int grid = n_tiles < GRID ? n_tiles : GRID;
    segment_top4_kernel<<<grid, WAVE, 0, stream>>>(
        row_ptr, scores, vals_out, idx_out, n_nodes, n_edges, n_tiles);
}

// Round 3
// 157.073 us; speedup vs baseline: 1.2330x; 1.1584x over previous
//
#include <hip/hip_runtime.h>
#include <math.h>

#define TOPK 4
#define BLOCK 256

// One node per thread, zero LDS. Edge scores have no reuse, so LDS staging
// only ever bought coalescing -- at the cost of 16% occupancy and an LDS
// round-trip on the scan's critical path. Instead: per-lane unit-stride
// global float4 reads (line locality via L1/L2/L3; input is ~L3-resident),
// hidden by ~8 waves/SIMD of TLP. __launch_bounds__(256,8) caps VGPR at 64
// so all ~7816 waves of the grid are co-resident in one generation.
__global__ __launch_bounds__(BLOCK, 8) void segment_top4_kernel(
    const int* __restrict__ row_ptr,
    const float* __restrict__ scores,
    float* __restrict__ vals_out,   // [N,4] float32
    float* __restrict__ idx_out,    // [N,4] indices as float32
    int n_nodes, int n_edges)
{
    int node = blockIdx.x * BLOCK + threadIdx.x;
    if (node >= n_nodes) return;

    int sb = row_ptr[node];
    int se = row_ptr[node + 1];

    // Insertion network, proven exact vs reference (strict '>' while
    // scanning in increasing edge order == score desc, index asc).
    float v0 = -INFINITY, v1 = -INFINITY, v2 = -INFINITY, v3 = -INFINITY;
    int   i0 = -1, i1 = -1, i2 = -1, i3 = -1;
    auto ins = [&](float s, int ei) {
        bool g0 = s > v0, g1 = s > v1, g2 = s > v2, g3 = s > v3;
        v3 = g3 ? (g2 ? v2 : s) : v3;  i3 = g3 ? (g2 ? i2 : ei) : i3;
        v2 = g2 ? (g1 ? v1 : s) : v2;  i2 = g2 ? (g1 ? i1 : ei) : i2;
        v1 = g1 ? (g0 ? v0 : s) : v1;  i1 = g1 ? (g0 ? i0 : ei) : i1;
        v0 = g0 ? s : v0;              i0 = g0 ? ei : i0;
    };

    unsigned rng = (unsigned)(se - sb);   // live iff (unsigned)(ei - sb) < rng
    int e0 = sb & ~3;                     // 16B-aligned quad start

    if (se <= n_edges - 8) {
        // Fast path (all but the last couple of nodes in the array): both
        // quads of every iteration are in-bounds by construction
        // (max read index e+7 <= se+6 <= n_edges-2).
        for (int e = e0; e < se; e += 8) {
            float4 qa = *(const float4*)(scores + e);
            float4 qb = *(const float4*)(scores + e + 4);
            unsigned off = (unsigned)(e - sb);   // wraps below sb -> masked
            ins(off      < rng ? qa.x : -INFINITY, e);
            ins(off + 1u < rng ? qa.y : -INFINITY, e + 1);
            ins(off + 2u < rng ? qa.z : -INFINITY, e + 2);
            ins(off + 3u < rng ? qa.w : -INFINITY, e + 3);
            ins(off + 4u < rng ? qb.x : -INFINITY, e + 4);
            ins(off + 5u < rng ? qb.y : -INFINITY, e + 5);
            ins(off + 6u < rng ? qb.z : -INFINITY, e + 6);
            ins(off + 7u < rng ? qb.w : -INFINITY, e + 7);
        }
    } else {
        // Tail path: clamp quad starts to the last in-bounds aligned quad.
        // A clamped quad shifts its window backward, so additionally mask
        // elements below the quad's intended start (prevents duplicate
        // insertion of already-processed indices). Live-element order
        // remains strictly increasing, preserving the tie-break.
        int clampq = n_edges - 4;
        for (int e = e0; e < se; e += 8) {
            int a0 = min(e, clampq);
            int a1 = min(e + 4, clampq);
            float4 qa = *(const float4*)(scores + a0);
            float4 qb = *(const float4*)(scores + a1);
            auto m = [&](int ei, int qs) -> bool {
                return ((unsigned)(ei - sb) < rng) && (ei >= qs);
            };
            ins(m(a0,     e) ? qa.x : -INFINITY, a0);
            ins(m(a0 + 1, e) ? qa.y : -INFINITY, a0 + 1);
            ins(m(a0 + 2, e) ? qa.z : -INFINITY, a0 + 2);
            ins(m(a0 + 3, e) ? qa.w : -INFINITY, a0 + 3);
            ins(m(a1,     e + 4) ? qb.x : -INFINITY, a1);
            ins(m(a1 + 1, e + 4) ? qb.y : -INFINITY, a1 + 1);
            ins(m(a1 + 2, e + 4) ? qb.z : -INFINITY, a1 + 2);
            ins(m(a1 + 3, e + 4) ? qb.w : -INFINITY, a1 + 3);
        }
    }

    // ---- store (coalesced: consecutive threads -> consecutive float4) ----
    float4 vo, io;
    vo.x = v0; vo.y = v1; vo.z = v2; vo.w = v3;
    io.x = (float)i0; io.y = (float)i1; io.z = (float)i2; io.w = (float)i3;
    *(float4*)(vals_out + (size_t)node * 4) = vo;
    *(float4*)(idx_out + (size_t)node * 4) = io;
}

extern "C" void kernel_launch(void* const* d_in, const int* in_sizes, int n_in,
                              void* d_out, int out_size, void* d_ws, size_t ws_size,
                              hipStream_t stream)
{
    const int*   row_ptr = (const int*)d_in[0];
    const float* scores  = (const float*)d_in[1];
    int n_nodes = in_sizes[0] - 1;
    int n_edges = in_sizes[1];

    float* out      = (float*)d_out;
    float* vals_out = out;                           // first N*4 floats
    float* idx_out  = out + (size_t)n_nodes * TOPK;  // next N*4 floats (idx as f32)

    int grid = (n_nodes + BLOCK - 1) / BLOCK;
    segment_top4_kernel<<<grid, BLOCK, 0, stream>>>(
        row_ptr, scores, vals_out, idx_out, n_nodes, n_edges);
}

// Round 4
// 145.826 us; speedup vs baseline: 1.3281x; 1.0771x over previous
//
#include <hip/hip_runtime.h>
#include <math.h>

#define TOPK 4
#define BLOCK 256
#define WPB 4                  // waves per block
#define CHUNK 512              // floats per LDS chunk (2 KB)
#define CPAD 4

// Wave-private chunked staging: each wave streams its 64-node tile range
// through two 2KB LDS chunks. Coalesced global->LDS DMA (fetch ~= input
// size) + only 4.1 KB LDS per wave -> 32 waves/CU (8/SIMD) of TLP hides
// both DMA and LDS-read latency. No syncthreads anywhere (waves private).
__global__ __launch_bounds__(BLOCK, 8) void segment_top4_kernel(
    const int* __restrict__ row_ptr,
    const float* __restrict__ scores,
    float* __restrict__ vals_out,   // [N,4] float32
    float* __restrict__ idx_out,    // [N,4] indices as float32
    int n_nodes, int n_edges, int n_tiles)
{
    __shared__ float lds[WPB][2][CHUNK + CPAD];

    int lane = threadIdx.x & 63;
    int wid  = threadIdx.x >> 6;
    int tile = blockIdx.x * WPB + wid;
    if (tile >= n_tiles) return;          // wave-uniform exit

    // Per-lane segment bounds; out-of-range lanes get sb=se=n_edges so their
    // range is empty AND lane63's 'se' still ends the tile correctly.
    int node = (tile << 6) + lane;
    int sb = row_ptr[min(node, n_nodes)];
    int se = row_ptr[min(node + 1, n_nodes)];

    int base = __shfl(sb, 0) & ~3;        // tile start, 16B-aligned down
    int tend = __shfl(se, 63);            // tile end (== n_edges on last tile)

    unsigned rng = (unsigned)(se - sb);   // live iff (unsigned)(ei-sb) < rng
    int q0 = sb & ~3;

    // ---- f64-packed key: [sign=0][mono(score) 32b][~idx 31b] ----
    // mono: order-preserving f32->u32 map; inv-idx: larger key == smaller
    // index. Key order == (score desc, index asc); keys unique; all keys
    // > 0.0 and finite (exponent field all-ones is unreachable for any
    // finite/inf f32 score). Empty slot = 0.0, never displaces anything.
    double d0 = 0.0, d1 = 0.0, d2 = 0.0, d3 = 0.0;
    auto mk = [&](float s, int ei, bool live) -> double {
        unsigned u = __float_as_uint(s);
        unsigned mono = u ^ (0x80000000u | (unsigned)((int)u >> 31));
        unsigned inv = 0x7FFFFFFFu - (unsigned)ei;
        unsigned lo = (mono << 31) | inv;
        unsigned hi = mono >> 1;
        unsigned long long k = ((unsigned long long)hi << 32) | lo;
        k = live ? k : 0ULL;
        return __longlong_as_double((long long)k);
    };
    // Top-4 keep via 4 max + 3 min (single-instr v_max_f64/v_min_f64),
    // order-independent, depth 2 per element.
    auto ins = [&](double c) {
        double m0 = fmin(d0, c);
        double m1 = fmin(d1, c);
        double m2 = fmin(d2, c);
        d0 = fmax(d0, c);
        d1 = fmax(d1, m0);
        d2 = fmax(d2, m1);
        d3 = fmax(d3, m2);
    };

    const int clampq = n_edges - 4;
    auto dma = [&](int cb, int b) {
#pragma unroll
        for (int r = 0; r < CHUNK / 256; ++r) {        // 2 x 16B/lane rounds
            int src = cb + (r << 8) + (lane << 2);
            src = src < clampq ? src : clampq;          // clamped lanes masked
            __builtin_amdgcn_global_load_lds(
                (const __attribute__((address_space(1))) void*)(scores + src),
                (__attribute__((address_space(3))) void*)(&lds[wid][b][r << 8]),
                16, 0, 0);
        }
    };

    dma(base, 0);
    int cur = 0;
    for (int cb = base; cb < tend; cb += CHUNK) {
        int nb = cb + CHUNK;
        if (nb < tend) {
            dma(nb, cur ^ 1);                           // next chunk in flight
            asm volatile("s_waitcnt vmcnt(2)" ::: "memory");  // drain cur only
        } else {
            asm volatile("s_waitcnt vmcnt(0)" ::: "memory");
        }

        // Per-lane window of full quads inside this chunk. whi <= nb, so LDS
        // reads never touch the pad; elements >= se are masked by 'rng'.
        const float* b = lds[wid][cur];
        int wlo = max(q0, cb);                          // 4-aligned
        int whi = min((se + 3) & ~3, nb);
        for (int e = wlo; e < whi; e += 4) {
            float4 q = *(const float4*)(b + (e - cb));
            unsigned off = (unsigned)(e - sb);          // wraps below sb
            ins(mk(q.x, e,     off      < rng));
            ins(mk(q.y, e + 1, off + 1u < rng));
            ins(mk(q.z, e + 2, off + 2u < rng));
            ins(mk(q.w, e + 3, off + 3u < rng));
        }
        cur ^= 1;
    }

    // ---- decode + store ----
    if (node < n_nodes) {
        auto dec = [](double d, float& v, float& fi) {
            unsigned long long k = (unsigned long long)__double_as_longlong(d);
            if (k == 0ULL) { v = -INFINITY; fi = -1.0f; return; }
            unsigned mono = (unsigned)(k >> 31);
            unsigned u = (mono & 0x80000000u) ? (mono ^ 0x80000000u) : ~mono;
            v = __uint_as_float(u);
            fi = (float)(int)(0x7FFFFFFFu - ((unsigned)k & 0x7FFFFFFFu));
        };
        float4 vo, io;
        dec(d0, vo.x, io.x); dec(d1, vo.y, io.y);
        dec(d2, vo.z, io.z); dec(d3, vo.w, io.w);
        *(float4*)(vals_out + (size_t)node * 4) = vo;
        *(float4*)(idx_out + (size_t)node * 4) = io;
    }
}

extern "C" void kernel_launch(void* const* d_in, const int* in_sizes, int n_in,
                              void* d_out, int out_size, void* d_ws, size_t ws_size,
                              hipStream_t stream)
{
    const int*   row_ptr = (const int*)d_in[0];
    const float* scores  = (const float*)d_in[1];
    int n_nodes = in_sizes[0] - 1;
    int n_edges = in_sizes[1];
    int n_tiles = (n_nodes + 63) >> 6;

    float* out      = (float*)d_out;
    float* vals_out = out;                           // first N*4 floats
    float* idx_out  = out + (size_t)n_nodes * TOPK;  // next N*4 floats (idx as f32)

    int grid = (n_tiles + WPB - 1) / WPB;
    segment_top4_kernel<<<grid, BLOCK, 0, stream>>>(
        row_ptr, scores, vals_out, idx_out, n_nodes, n_edges, n_tiles);
}